// Round 5
// baseline (290.109 us; speedup 1.0000x reference)
//
#include <hip/hip_runtime.h>
#include <cstdint>
#include <cstddef>

#define B_DIM 16
#define C_DIM 1024
#define N_DIM 2304   // 48*48

typedef _Float16 f16;
typedef _Float16 f16x8 __attribute__((ext_vector_type(8)));
typedef _Float16 f16x4 __attribute__((ext_vector_type(4)));
typedef float f32x4 __attribute__((ext_vector_type(4)));

__device__ __forceinline__ void gload_lds16(const void* g, void* l) {
  __builtin_amdgcn_global_load_lds(
      (const __attribute__((address_space(1))) unsigned int*)g,
      (__attribute__((address_space(3))) unsigned int*)l, 16, 0, 0);
}

// K1: x fp32 [C][N] -> qh f16 [C][N] (row-major) and qt f16 [N][C] (transposed)
__global__ __launch_bounds__(256)
void k_cast_transpose(const float* __restrict__ x, f16* __restrict__ qh,
                      f16* __restrict__ qt) {
  __shared__ f16 t[64][65];
  const int z = blockIdx.z;
  const int c0 = blockIdx.y * 64, n0 = blockIdx.x * 64;
  const int tid = threadIdx.x;
  const int r = tid >> 2;          // 0..63 (row within tile)
  const int cq = (tid & 3) << 4;   // 0,16,32,48 (col chunk)
  const float* xp = x + ((size_t)z * C_DIM + c0 + r) * N_DIM + n0 + cq;
  float4 v0 = ((const float4*)xp)[0];
  float4 v1 = ((const float4*)xp)[1];
  float4 v2 = ((const float4*)xp)[2];
  float4 v3 = ((const float4*)xp)[3];
  float vv[16] = {v0.x, v0.y, v0.z, v0.w, v1.x, v1.y, v1.z, v1.w,
                  v2.x, v2.y, v2.z, v2.w, v3.x, v3.y, v3.z, v3.w};
  f16 h[16];
#pragma unroll
  for (int j = 0; j < 16; ++j) h[j] = (f16)vv[j];
  f16* qp = qh + ((size_t)z * C_DIM + c0 + r) * N_DIM + n0 + cq;
  ((f16x8*)qp)[0] = *(const f16x8*)&h[0];
  ((f16x8*)qp)[1] = *(const f16x8*)&h[8];
#pragma unroll
  for (int j = 0; j < 16; ++j) t[r][cq + j] = h[j];
  __syncthreads();
  f16 o[16];
#pragma unroll
  for (int j = 0; j < 16; ++j) o[j] = t[cq + j][r];
  f16* tp = qt + ((size_t)z * N_DIM + n0 + r) * C_DIM + c0 + cq;
  ((f16x8*)tp)[0] = *(const f16x8*)&o[0];
  ((f16x8*)tp)[1] = *(const f16x8*)&o[8];
}

// K3: one WAVE per row of E: attn = exp(min - e)/sum, f16 in-place.
__global__ __launch_bounds__(256)
void k_softmax(float* __restrict__ eng) {
  const int w = threadIdx.x >> 6, lane = threadIdx.x & 63;
  const int c = blockIdx.x * 4 + w, z = blockIdx.y;
  float* erow = eng + ((size_t)z * C_DIM + c) * C_DIM;
  float4 v[4];
#pragma unroll
  for (int i = 0; i < 4; ++i) v[i] = ((const float4*)erow)[lane + i * 64];
  float lmin = v[0].x;
#pragma unroll
  for (int i = 0; i < 4; ++i)
    lmin = fminf(lmin, fminf(fminf(v[i].x, v[i].y), fminf(v[i].z, v[i].w)));
#pragma unroll
  for (int s = 32; s > 0; s >>= 1) lmin = fminf(lmin, __shfl_xor(lmin, s, 64));
  float p[16];
  float ls = 0.f;
#pragma unroll
  for (int i = 0; i < 4; ++i) {
    p[i * 4 + 0] = __expf(lmin - v[i].x);
    p[i * 4 + 1] = __expf(lmin - v[i].y);
    p[i * 4 + 2] = __expf(lmin - v[i].z);
    p[i * 4 + 3] = __expf(lmin - v[i].w);
    ls += p[i * 4] + p[i * 4 + 1] + p[i * 4 + 2] + p[i * 4 + 3];
  }
#pragma unroll
  for (int s = 32; s > 0; s >>= 1) ls += __shfl_xor(ls, s, 64);
  const float inv = 1.0f / ls;
#pragma unroll
  for (int i = 0; i < 4; ++i) {
    f16x4 o;
    o.x = (f16)(p[i * 4 + 0] * inv); o.y = (f16)(p[i * 4 + 1] * inv);
    o.z = (f16)(p[i * 4 + 2] * inv); o.w = (f16)(p[i * 4 + 3] * inv);
    *(f16x4*)((f16*)erow + (lane + i * 64) * 4) = o;
  }
}

// ------- 256x256 NT GEMM, cluster-pipelined, counted lgkm/vmcnt -----------
// 512 thr = 8 waves (2M x 4N), wave tile 128x64, K-tile 64 (2 planes of 32).
// LDS 128KB: A[2 buf][2 plane][256][32] @0, B same @65536; chunk^=(row>>1)&3.
// Per K-tile cluster: all 24 operand ds_reads were issued at END of prev
// cluster (order a0,b0,b1,a1); consume via lgkmcnt(12)/(8)/(0) so half the
// LDS drain hides under MFMA. One full-tile stage (8 gloads) per cluster,
// vmcnt(8) steady state. 2 barriers per K-tile.

#define BARR __builtin_amdgcn_s_barrier()
#define SBR __builtin_amdgcn_sched_barrier(0)
#define LGKM(N) asm volatile("s_waitcnt lgkmcnt(" #N ")" ::: "memory")
#define VM8 asm volatile("s_waitcnt vmcnt(8)" ::: "memory")
#define VM0 asm volatile("s_waitcnt vmcnt(0)" ::: "memory")
#define PRIO1 __builtin_amdgcn_s_setprio(1)
#define PRIO0 __builtin_amdgcn_s_setprio(0)

#define STA(KT, H) { const int d_ = (KT) & 1;                                  \
    const f16* g_ = Ap + ((H) ? gA1 : gA0) + (size_t)(KT) * 64;                \
    char* l_ = sh + d_ * 32768 + (H) * 8192 + tid * 16;                        \
    gload_lds16(g_, l_); gload_lds16(g_ + 32, l_ + 16384); }

#define STB(KT, H) { const int d_ = (KT) & 1;                                  \
    const f16* g_ = Bp + ((H) ? gB1 : gB0) + (size_t)(KT) * 64;                \
    char* l_ = sh + 65536 + d_ * 32768 + (H) * 8192 + tid * 16;                \
    gload_lds16(g_, l_); gload_lds16(g_ + 32, l_ + 16384); }

#define STAGE(KT) { STA(KT, 0); STA(KT, 1); STB(KT, 0); STB(KT, 1); }

#define RD_A(SET, BASE, MH) _Pragma("unroll") for (int j_ = 0; j_ < 4; ++j_)   \
    _Pragma("unroll") for (int p_ = 0; p_ < 2; ++p_)                           \
      SET[j_ * 2 + p_] =                                                       \
          *(const f16x8*)((BASE) + p_ * 16384 + (MH) * 8192 + j_ * 1024);

#define RD_B(SET, BASE, NH) _Pragma("unroll") for (int i_ = 0; i_ < 2; ++i_)   \
    _Pragma("unroll") for (int p_ = 0; p_ < 2; ++p_)                           \
      SET[i_ * 2 + p_] =                                                       \
          *(const f16x8*)((BASE) + p_ * 16384 + (NH) * 8192 + i_ * 1024);

// issue order (FIFO for counted lgkm): a0(8), b0(4), b1(4), a1(8)
#define READS(TT) {                                                            \
    const char* Ab_ = sh + ((TT) & 1) * 32768 + aBase;                         \
    const char* Bb_ = sh + 65536 + ((TT) & 1) * 32768 + bBase;                 \
    RD_A(a0r, Ab_, 0); SBR; RD_B(b0r, Bb_, 0); SBR;                            \
    RD_B(b1r, Bb_, 1); SBR; RD_A(a1r, Ab_, 1); SBR; }

#define MMQ(MH, NH, A_, B_) _Pragma("unroll") for (int j_ = 0; j_ < 4; ++j_)   \
    _Pragma("unroll") for (int i_ = 0; i_ < 2; ++i_)                           \
    _Pragma("unroll") for (int k_ = 0; k_ < 2; ++k_)                           \
      acc[(MH) * 4 + j_][(NH) * 2 + i_] =                                      \
          __builtin_amdgcn_mfma_f32_16x16x32_f16(                              \
              A_[j_ * 2 + k_], B_[i_ * 2 + k_],                                \
              acc[(MH) * 4 + j_][(NH) * 2 + i_], 0, 0, 0);

template <int KD, int LDA, int LDB, bool ADDX>
__global__ __launch_bounds__(512, 2)
void k_gemm256(const f16* __restrict__ Ab, const f16* __restrict__ Bb,
               size_t astride, size_t bstride, float* __restrict__ Cb,
               size_t cstride, int ldc, const f16* __restrict__ Xb,
               int nbn, int perb) {
  constexpr int NT = KD / 64;
  static_assert(NT >= 4, "need >= 4 K-tiles");
  __shared__ char sh[131072];
  const int tid = threadIdx.x, lane = tid & 63, wid = tid >> 6;
  const int wm = wid >> 2, wn = wid & 3;   // 2 x 4 waves

  // bijective XCD swizzle (m204)
  const int nwg = gridDim.x, orig = blockIdx.x;
  const int qq = nwg >> 3, rr8 = nwg & 7, xcd = orig & 7;
  const int id = (xcd < rr8 ? xcd * (qq + 1) : rr8 * (qq + 1) + (xcd - rr8) * qq)
                 + (orig >> 3);
  const int z = id / perb, t = id - z * perb;
  const int bm = (t / nbn) * 256, bn = (t - (t / nbn) * nbn) * 256;

  const f16* Ap = Ab + z * astride + (size_t)bm * LDA;
  const f16* Bp = Bb + z * bstride + (size_t)bn * LDB;

  // staging: thread covers row rq (of a 128-row half), inverse-swizzled chunk
  const int rq = tid >> 2;
  const int cpr = (tid & 3) ^ ((tid >> 3) & 3);
  const size_t gA0 = (size_t)rq * LDA + cpr * 8;
  const size_t gA1 = gA0 + (size_t)128 * LDA;
  const size_t gB0 = (size_t)rq * LDB + cpr * 8;
  const size_t gB1 = gB0 + (size_t)128 * LDB;

  // fragment base offsets: swizzle chunk ((lane>>4)^((lane&15)>>1))&3 is
  // invariant across frag rows (row steps of 16/32/64 keep (row>>1)&3 fixed)
  const int swz = ((lane >> 4) ^ ((lane & 15) >> 1)) & 3;
  const int aBase = (wm * 64 + (lane & 15)) * 64 + swz * 16;
  const int bBase = (wn * 32 + (lane & 15)) * 64 + swz * 16;

  f32x4 acc[8][4] = {};
  f16x8 a0r[8], a1r[8], b0r[4], b1r[4];

  // prologue: stage tiles 0,1 (16 gloads); tile0 landed after VM8
  STAGE(0); STAGE(1);
  VM8; BARR; SBR;
  READS(0);

  for (int T = 0; T < NT; ++T) {
    LGKM(12); SBR; PRIO1; MMQ(0, 0, a0r, b0r); PRIO0;   // a0,b0 ready
    LGKM(8);  SBR; PRIO1; MMQ(0, 1, a0r, b1r); PRIO0;   // +b1 (drained under Q00)
    LGKM(0);  SBR; PRIO1; MMQ(1, 1, a1r, b1r);          // +a1
                          MMQ(1, 0, a1r, b0r); PRIO0;
    if (T < NT - 1) {
      BARR; SBR;                       // all waves done reading buf T&1
      if (T < NT - 2) { STAGE(T + 2); VM8; }   // drains tile T+1's stages
      else { VM0; }
      BARR; SBR;                       // tile T+1 globally visible in LDS
      READS(T + 1);
    }
  }

  // epilogue (residual read as f16 when ADDX)
  float* Cp = Cb + z * cstride;
  const f16* Xp = Xb + z * cstride;
#pragma unroll
  for (int mi = 0; mi < 8; ++mi) {
    const int row0 = bm + ((mi < 4) ? wm * 64 + mi * 16
                                    : 128 + wm * 64 + (mi - 4) * 16) +
                     (lane >> 4) * 4;
#pragma unroll
    for (int ni = 0; ni < 4; ++ni) {
      const int col = bn + ((ni < 2) ? wn * 32 + ni * 16
                                     : 128 + wn * 32 + (ni - 2) * 16) +
                      (lane & 15);
#pragma unroll
      for (int j = 0; j < 4; ++j) {
        const size_t idx = (size_t)(row0 + j) * ldc + col;
        float v = acc[mi][ni][j];
        if constexpr (ADDX) v += (float)Xp[idx];
        Cp[idx] = v;
      }
    }
  }
}

extern "C" void kernel_launch(void* const* d_in, const int* in_sizes, int n_in,
                              void* d_out, int out_size, void* d_ws,
                              size_t ws_size, hipStream_t stream) {
  const float* x = (const float*)d_in[0];
  float* out = (float*)d_out;
  const size_t qbytes = (size_t)C_DIM * N_DIM * sizeof(f16);   // 4.72 MB
  const size_t ebytes = (size_t)C_DIM * C_DIM * sizeof(float); // 4.19 MB
  const size_t per_batch = 2 * qbytes + ebytes;                // 13.6 MB
  int G = (int)(ws_size / per_batch);
  if (G > B_DIM) G = B_DIM;
  if (G < 1) G = 1;

  f16* qh = (f16*)d_ws;
  f16* qt = qh + (size_t)G * C_DIM * N_DIM;
  float* eng = (float*)(qt + (size_t)G * C_DIM * N_DIM);

  for (int b0 = 0; b0 < B_DIM; b0 += G) {
    const int g = (B_DIM - b0 < G) ? (B_DIM - b0) : G;
    const float* xg = x + (size_t)b0 * C_DIM * N_DIM;
    float* og = out + (size_t)b0 * C_DIM * N_DIM;

    k_cast_transpose<<<dim3(N_DIM / 64, C_DIM / 64, g), 256, 0, stream>>>(
        xg, qh, qt);

    // E = qh . qh^T  (M=N=C, K=N_DIM); 16 tiles/batch, XCD-swizzled 1D grid
    k_gemm256<N_DIM, N_DIM, N_DIM, false>
        <<<dim3(16 * g), 512, 0, stream>>>(
            qh, qh, (size_t)C_DIM * N_DIM, (size_t)C_DIM * N_DIM, eng,
            (size_t)C_DIM * C_DIM, C_DIM, nullptr, 4, 16);

    // attn = softmax(min - E) f16 in-place; one wave per row
    k_softmax<<<dim3(C_DIM / 4, g), 256, 0, stream>>>(eng);

    // out = attn . qt^T + qh(residual, f16)   (M=C, N=N_DIM, K=C)
    k_gemm256<C_DIM, 2 * C_DIM, C_DIM, true>
        <<<dim3(36 * g), 512, 0, stream>>>(
            (const f16*)eng, qt, (size_t)2 * C_DIM * C_DIM,
            (size_t)N_DIM * C_DIM, og, (size_t)C_DIM * N_DIM, N_DIM,
            qh, 9, 36);
  }
}

// Round 6
// 273.277 us; speedup vs baseline: 1.0616x; 1.0616x over previous
//
#include <hip/hip_runtime.h>
#include <cstdint>
#include <cstddef>

#define B_DIM 16
#define C_DIM 1024
#define N_DIM 2304   // 48*48

typedef _Float16 f16;
typedef _Float16 f16x8 __attribute__((ext_vector_type(8)));
typedef _Float16 f16x4 __attribute__((ext_vector_type(4)));
typedef float f32x4 __attribute__((ext_vector_type(4)));

__device__ __forceinline__ void gload_lds16(const void* g, void* l) {
  __builtin_amdgcn_global_load_lds(
      (const __attribute__((address_space(1))) unsigned int*)g,
      (__attribute__((address_space(3))) unsigned int*)l, 16, 0, 0);
}

// K1: x fp32 [C][N] -> qh f16 [C][N] (row-major) and qt f16 [N][C] (transposed)
__global__ __launch_bounds__(256)
void k_cast_transpose(const float* __restrict__ x, f16* __restrict__ qh,
                      f16* __restrict__ qt) {
  __shared__ f16 t[64][65];
  const int z = blockIdx.z;
  const int c0 = blockIdx.y * 64, n0 = blockIdx.x * 64;
  const int tid = threadIdx.x;
  const int r = tid >> 2;          // 0..63 (row within tile)
  const int cq = (tid & 3) << 4;   // 0,16,32,48 (col chunk)
  const float* xp = x + ((size_t)z * C_DIM + c0 + r) * N_DIM + n0 + cq;
  float4 v0 = ((const float4*)xp)[0];
  float4 v1 = ((const float4*)xp)[1];
  float4 v2 = ((const float4*)xp)[2];
  float4 v3 = ((const float4*)xp)[3];
  float vv[16] = {v0.x, v0.y, v0.z, v0.w, v1.x, v1.y, v1.z, v1.w,
                  v2.x, v2.y, v2.z, v2.w, v3.x, v3.y, v3.z, v3.w};
  f16 h[16];
#pragma unroll
  for (int j = 0; j < 16; ++j) h[j] = (f16)vv[j];
  f16* qp = qh + ((size_t)z * C_DIM + c0 + r) * N_DIM + n0 + cq;
  ((f16x8*)qp)[0] = *(const f16x8*)&h[0];
  ((f16x8*)qp)[1] = *(const f16x8*)&h[8];
#pragma unroll
  for (int j = 0; j < 16; ++j) t[r][cq + j] = h[j];
  __syncthreads();
  f16 o[16];
#pragma unroll
  for (int j = 0; j < 16; ++j) o[j] = t[cq + j][r];
  f16* tp = qt + ((size_t)z * N_DIM + n0 + r) * C_DIM + c0 + cq;
  ((f16x8*)tp)[0] = *(const f16x8*)&o[0];
  ((f16x8*)tp)[1] = *(const f16x8*)&o[8];
}

// K3: one WAVE per row of E: attn = exp(min - e)/sum, f16 in-place.
__global__ __launch_bounds__(256)
void k_softmax(float* __restrict__ eng) {
  const int w = threadIdx.x >> 6, lane = threadIdx.x & 63;
  const int c = blockIdx.x * 4 + w, z = blockIdx.y;
  float* erow = eng + ((size_t)z * C_DIM + c) * C_DIM;
  float4 v[4];
#pragma unroll
  for (int i = 0; i < 4; ++i) v[i] = ((const float4*)erow)[lane + i * 64];
  float lmin = v[0].x;
#pragma unroll
  for (int i = 0; i < 4; ++i)
    lmin = fminf(lmin, fminf(fminf(v[i].x, v[i].y), fminf(v[i].z, v[i].w)));
#pragma unroll
  for (int s = 32; s > 0; s >>= 1) lmin = fminf(lmin, __shfl_xor(lmin, s, 64));
  float p[16];
  float ls = 0.f;
#pragma unroll
  for (int i = 0; i < 4; ++i) {
    p[i * 4 + 0] = __expf(lmin - v[i].x);
    p[i * 4 + 1] = __expf(lmin - v[i].y);
    p[i * 4 + 2] = __expf(lmin - v[i].z);
    p[i * 4 + 3] = __expf(lmin - v[i].w);
    ls += p[i * 4] + p[i * 4 + 1] + p[i * 4 + 2] + p[i * 4 + 3];
  }
#pragma unroll
  for (int s = 32; s > 0; s >>= 1) ls += __shfl_xor(ls, s, 64);
  const float inv = 1.0f / ls;
#pragma unroll
  for (int i = 0; i < 4; ++i) {
    f16x4 o;
    o.x = (f16)(p[i * 4 + 0] * inv); o.y = (f16)(p[i * 4 + 1] * inv);
    o.z = (f16)(p[i * 4 + 2] * inv); o.w = (f16)(p[i * 4 + 3] * inv);
    *(f16x4*)((f16*)erow + (lane + i * 64) * 4) = o;
  }
}

#define BARR __builtin_amdgcn_s_barrier()
#define SBR __builtin_amdgcn_sched_barrier(0)
#define LGKM(N) asm volatile("s_waitcnt lgkmcnt(" #N ")" ::: "memory")
#define VM8 asm volatile("s_waitcnt vmcnt(8)" ::: "memory")
#define VM0 asm volatile("s_waitcnt vmcnt(0)" ::: "memory")
#define PRIO1 __builtin_amdgcn_s_setprio(1)
#define PRIO0 __builtin_amdgcn_s_setprio(0)

// =================== 256x256 NT GEMM (QK; unchanged from R4) ===============
#define STA(KT, H) { const int d_ = (KT) & 1;                                  \
    const f16* g_ = Ap + ((H) ? gA1 : gA0) + (size_t)(KT) * 64;                \
    char* l_ = sh + d_ * 32768 + (H) * 8192 + tid * 16;                        \
    gload_lds16(g_, l_); gload_lds16(g_ + 32, l_ + 16384); }

#define STB(KT, H) { const int d_ = (KT) & 1;                                  \
    const f16* g_ = Bp + ((H) ? gB1 : gB0) + (size_t)(KT) * 64;                \
    char* l_ = sh + 65536 + d_ * 32768 + (H) * 8192 + tid * 16;                \
    gload_lds16(g_, l_); gload_lds16(g_ + 32, l_ + 16384); }

#define STAGE(KT) { STA(KT, 0); STA(KT, 1); STB(KT, 0); STB(KT, 1); }

#define RD_A(SET, BASE, MH) _Pragma("unroll") for (int j_ = 0; j_ < 4; ++j_)   \
    _Pragma("unroll") for (int p_ = 0; p_ < 2; ++p_)                           \
      SET[j_ * 2 + p_] =                                                       \
          *(const f16x8*)((BASE) + p_ * 16384 + (MH) * 8192 + j_ * 1024);

#define RD_B(SET, BASE, NH) _Pragma("unroll") for (int i_ = 0; i_ < 2; ++i_)   \
    _Pragma("unroll") for (int p_ = 0; p_ < 2; ++p_)                           \
      SET[i_ * 2 + p_] =                                                       \
          *(const f16x8*)((BASE) + p_ * 16384 + (NH) * 8192 + i_ * 1024);

#define READS(TT) {                                                            \
    const char* Ab_ = sh + ((TT) & 1) * 32768 + aBase;                         \
    const char* Bb_ = sh + 65536 + ((TT) & 1) * 32768 + bBase;                 \
    RD_A(a0r, Ab_, 0); SBR; RD_B(b0r, Bb_, 0); SBR;                            \
    RD_B(b1r, Bb_, 1); SBR; RD_A(a1r, Ab_, 1); SBR; }

#define MMQ(MH, NH, A_, B_) _Pragma("unroll") for (int j_ = 0; j_ < 4; ++j_)   \
    _Pragma("unroll") for (int i_ = 0; i_ < 2; ++i_)                           \
    _Pragma("unroll") for (int k_ = 0; k_ < 2; ++k_)                           \
      acc[(MH) * 4 + j_][(NH) * 2 + i_] =                                      \
          __builtin_amdgcn_mfma_f32_16x16x32_f16(                              \
              A_[j_ * 2 + k_], B_[i_ * 2 + k_],                                \
              acc[(MH) * 4 + j_][(NH) * 2 + i_], 0, 0, 0);

template <int KD, int LDA, int LDB, bool ADDX>
__global__ __launch_bounds__(512, 2)
void k_gemm256(const f16* __restrict__ Ab, const f16* __restrict__ Bb,
               size_t astride, size_t bstride, float* __restrict__ Cb,
               size_t cstride, int ldc, const f16* __restrict__ Xb,
               int nbn, int perb) {
  constexpr int NT = KD / 64;
  static_assert(NT >= 4, "need >= 4 K-tiles");
  __shared__ char sh[131072];
  const int tid = threadIdx.x, lane = tid & 63, wid = tid >> 6;
  const int wm = wid >> 2, wn = wid & 3;   // 2 x 4 waves

  const int nwg = gridDim.x, orig = blockIdx.x;
  const int qq = nwg >> 3, rr8 = nwg & 7, xcd = orig & 7;
  const int id = (xcd < rr8 ? xcd * (qq + 1) : rr8 * (qq + 1) + (xcd - rr8) * qq)
                 + (orig >> 3);
  const int z = id / perb, t = id - z * perb;
  const int bm = (t / nbn) * 256, bn = (t - (t / nbn) * nbn) * 256;

  const f16* Ap = Ab + z * astride + (size_t)bm * LDA;
  const f16* Bp = Bb + z * bstride + (size_t)bn * LDB;

  const int rq = tid >> 2;
  const int cpr = (tid & 3) ^ ((tid >> 3) & 3);
  const size_t gA0 = (size_t)rq * LDA + cpr * 8;
  const size_t gA1 = gA0 + (size_t)128 * LDA;
  const size_t gB0 = (size_t)rq * LDB + cpr * 8;
  const size_t gB1 = gB0 + (size_t)128 * LDB;

  const int swz = ((lane >> 4) ^ ((lane & 15) >> 1)) & 3;
  const int aBase = (wm * 64 + (lane & 15)) * 64 + swz * 16;
  const int bBase = (wn * 32 + (lane & 15)) * 64 + swz * 16;

  f32x4 acc[8][4] = {};
  f16x8 a0r[8], a1r[8], b0r[4], b1r[4];

  STAGE(0); STAGE(1);
  VM8; BARR; SBR;
  READS(0);

  for (int T = 0; T < NT; ++T) {
    LGKM(12); SBR; PRIO1; MMQ(0, 0, a0r, b0r); PRIO0;
    LGKM(8);  SBR; PRIO1; MMQ(0, 1, a0r, b1r); PRIO0;
    LGKM(0);  SBR; PRIO1; MMQ(1, 1, a1r, b1r);
                          MMQ(1, 0, a1r, b0r); PRIO0;
    if (T < NT - 1) {
      BARR; SBR;
      if (T < NT - 2) { STAGE(T + 2); VM8; }
      else { VM0; }
      BARR; SBR;
      READS(T + 1);
    }
  }

  float* Cp = Cb + z * cstride;
  const f16* Xp = Xb + z * cstride;
#pragma unroll
  for (int mi = 0; mi < 8; ++mi) {
    const int row0 = bm + ((mi < 4) ? wm * 64 + mi * 16
                                    : 128 + wm * 64 + (mi - 4) * 16) +
                     (lane >> 4) * 4;
#pragma unroll
    for (int ni = 0; ni < 4; ++ni) {
      const int col = bn + ((ni < 2) ? wn * 32 + ni * 16
                                     : 128 + wn * 32 + (ni - 2) * 16) +
                      (lane & 15);
#pragma unroll
      for (int j = 0; j < 4; ++j) {
        const size_t idx = (size_t)(row0 + j) * ldc + col;
        float v = acc[mi][ni][j];
        if constexpr (ADDX) v += (float)Xp[idx];
        Cp[idx] = v;
      }
    }
  }
}

// ========= 128x128 NT GEMM (PV): 64KB LDS => 2 resident blocks/CU =========
// 256 thr = 4 waves (2x2), wave tile 64x64 = 4x4 frags of 16x16x32.
// LDS: A[2 buf][2 plane][128][32] f16 @0 (32KB), B same @32768.
// Same XOR swizzle; counted lgkm 8/4/0 over 16 reads; vmcnt(8) steady.
// Cross-block overlap (2 independent barrier domains) hides stalls.

#define STG128(KT) { const int d_ = (KT) & 1;                                  \
    _Pragma("unroll") for (int g_ = 0; g_ < 4; ++g_)                           \
      gload_lds16(Ap + gSA + (size_t)(g_ & 1) * 64 * LDA + (g_ >> 1) * 32 +    \
                      (size_t)(KT) * 64,                                       \
                  sh + d_ * 16384 + g_ * 4096 + tid * 16);                     \
    _Pragma("unroll") for (int g_ = 0; g_ < 4; ++g_)                           \
      gload_lds16(Bp + gSB + (size_t)(g_ & 1) * 64 * LDB + (g_ >> 1) * 32 +    \
                      (size_t)(KT) * 64,                                       \
                  sh + 32768 + d_ * 16384 + g_ * 4096 + tid * 16); }

#define READS128(TT) {                                                         \
    const char* A_ = sh + ((TT) & 1) * 16384;                                  \
    const char* B_ = sh + 32768 + ((TT) & 1) * 16384;                          \
    _Pragma("unroll") for (int m_ = 0; m_ < 2; ++m_)                           \
    _Pragma("unroll") for (int p_ = 0; p_ < 2; ++p_)                           \
      a[m_ * 2 + p_] = *(const f16x8*)(A_ + p_ * 8192 + aBase + m_ * 1024);    \
    SBR;                                                                       \
    _Pragma("unroll") for (int n_ = 0; n_ < 2; ++n_)                           \
    _Pragma("unroll") for (int p_ = 0; p_ < 2; ++p_)                           \
      b[n_ * 2 + p_] = *(const f16x8*)(B_ + p_ * 8192 + bBase + n_ * 1024);    \
    SBR;                                                                       \
    _Pragma("unroll") for (int n_ = 0; n_ < 2; ++n_)                           \
    _Pragma("unroll") for (int p_ = 0; p_ < 2; ++p_)                           \
      b[4 + n_ * 2 + p_] =                                                     \
          *(const f16x8*)(B_ + p_ * 8192 + bBase + (2 + n_) * 1024);           \
    SBR;                                                                       \
    _Pragma("unroll") for (int m_ = 0; m_ < 2; ++m_)                           \
    _Pragma("unroll") for (int p_ = 0; p_ < 2; ++p_)                           \
      a[4 + m_ * 2 + p_] =                                                     \
          *(const f16x8*)(A_ + p_ * 8192 + aBase + (2 + m_) * 1024);           \
    SBR; }

#define MMQ128(MH, NH) _Pragma("unroll") for (int j_ = 0; j_ < 2; ++j_)        \
    _Pragma("unroll") for (int i_ = 0; i_ < 2; ++i_)                           \
    _Pragma("unroll") for (int k_ = 0; k_ < 2; ++k_)                           \
      acc[(MH) * 2 + j_][(NH) * 2 + i_] =                                      \
          __builtin_amdgcn_mfma_f32_16x16x32_f16(                              \
              a[((MH) * 2 + j_) * 2 + k_], b[((NH) * 2 + i_) * 2 + k_],        \
              acc[(MH) * 2 + j_][(NH) * 2 + i_], 0, 0, 0);

template <int KD, int LDA, int LDB>
__global__ __launch_bounds__(256, 2)
void k_gemm128(const f16* __restrict__ Ab, const f16* __restrict__ Bb,
               size_t astride, size_t bstride, float* __restrict__ Cb,
               size_t cstride, int ldc, const f16* __restrict__ Xb,
               int nbm, int perb) {
  constexpr int NT = KD / 64;
  static_assert(NT >= 4, "need >= 4 K-tiles");
  __shared__ char sh[65536];
  const int tid = threadIdx.x, lane = tid & 63, wid = tid >> 6;
  const int wm = wid >> 1, wn = wid & 1;   // 2 x 2 waves

  const int nwg = gridDim.x, orig = blockIdx.x;
  const int qq = nwg >> 3, rr8 = nwg & 7, xcd = orig & 7;
  const int id = (xcd < rr8 ? xcd * (qq + 1) : rr8 * (qq + 1) + (xcd - rr8) * qq)
                 + (orig >> 3);
  const int z = id / perb, t = id - z * perb;
  // tm-inner: 8 consecutive blocks share one B panel (256KB) + A panel in L2
  const int bm = (t % nbm) * 128, bn = (t / nbm) * 128;

  const f16* Ap = Ab + z * astride + (size_t)bm * LDA;
  const f16* Bp = Bb + z * bstride + (size_t)bn * LDB;

  const int rq = tid >> 2;                         // 0..63
  const int cs = (tid & 3) ^ ((rq >> 1) & 3);      // inverse-swizzled chunk
  const size_t gSA = (size_t)rq * LDA + cs * 8;
  const size_t gSB = (size_t)rq * LDB + cs * 8;

  const int swz = ((lane >> 4) ^ ((lane & 15) >> 1)) & 3;
  const int aBase = (wm * 64 + (lane & 15)) * 64 + swz * 16;
  const int bBase = (wn * 64 + (lane & 15)) * 64 + swz * 16;

  f32x4 acc[4][4] = {};
  f16x8 a[8], b[8];

  STG128(0); STG128(1);
  VM8; BARR; SBR;
  READS128(0);

  for (int T = 0; T < NT; ++T) {
    LGKM(8); SBR; PRIO1; MMQ128(0, 0); PRIO0;
    LGKM(4); SBR; PRIO1; MMQ128(0, 1); PRIO0;
    LGKM(0); SBR; PRIO1; MMQ128(1, 1); MMQ128(1, 0); PRIO0;
    if (T < NT - 1) {
      BARR; SBR;
      if (T < NT - 2) { STG128(T + 2); VM8; }
      else { VM0; }
      BARR; SBR;
      READS128(T + 1);
    }
  }

  float* Cp = Cb + z * cstride;
  const f16* Xp = Xb + z * cstride;
#pragma unroll
  for (int mi = 0; mi < 4; ++mi) {
    const int row0 = bm + wm * 64 + mi * 16 + (lane >> 4) * 4;
#pragma unroll
    for (int ni = 0; ni < 4; ++ni) {
      const int col = bn + wn * 64 + ni * 16 + (lane & 15);
#pragma unroll
      for (int j = 0; j < 4; ++j) {
        const size_t idx = (size_t)(row0 + j) * ldc + col;
        Cp[idx] = acc[mi][ni][j] + (float)Xp[idx];
      }
    }
  }
}

extern "C" void kernel_launch(void* const* d_in, const int* in_sizes, int n_in,
                              void* d_out, int out_size, void* d_ws,
                              size_t ws_size, hipStream_t stream) {
  const float* x = (const float*)d_in[0];
  float* out = (float*)d_out;
  const size_t qbytes = (size_t)C_DIM * N_DIM * sizeof(f16);   // 4.72 MB
  const size_t ebytes = (size_t)C_DIM * C_DIM * sizeof(float); // 4.19 MB
  const size_t per_batch = 2 * qbytes + ebytes;                // 13.6 MB
  int G = (int)(ws_size / per_batch);
  if (G > B_DIM) G = B_DIM;
  if (G < 1) G = 1;

  f16* qh = (f16*)d_ws;
  f16* qt = qh + (size_t)G * C_DIM * N_DIM;
  float* eng = (float*)(qt + (size_t)G * C_DIM * N_DIM);

  for (int b0 = 0; b0 < B_DIM; b0 += G) {
    const int g = (B_DIM - b0 < G) ? (B_DIM - b0) : G;
    const float* xg = x + (size_t)b0 * C_DIM * N_DIM;
    float* og = out + (size_t)b0 * C_DIM * N_DIM;

    k_cast_transpose<<<dim3(N_DIM / 64, C_DIM / 64, g), 256, 0, stream>>>(
        xg, qh, qt);

    // E = qh . qh^T  (M=N=C, K=N_DIM); 16 tiles/batch, XCD-swizzled 1D grid
    k_gemm256<N_DIM, N_DIM, N_DIM, false>
        <<<dim3(16 * g), 512, 0, stream>>>(
            qh, qh, (size_t)C_DIM * N_DIM, (size_t)C_DIM * N_DIM, eng,
            (size_t)C_DIM * C_DIM, C_DIM, nullptr, 4, 16);

    // attn = softmax(min - E) f16 in-place; one wave per row
    k_softmax<<<dim3(C_DIM / 4, g), 256, 0, stream>>>(eng);

    // out = attn . qt^T + qh(residual, f16)   (M=C, N=N_DIM, K=C)
    // 128x128 tiles: 8 (M) x 18 (N) = 144/batch; 2 resident blocks/CU
    k_gemm128<C_DIM, 2 * C_DIM, C_DIM>
        <<<dim3(144 * g), 256, 0, stream>>>(
            (const f16*)eng, qt, (size_t)2 * C_DIM * C_DIM,
            (size_t)N_DIM * C_DIM, og, (size_t)C_DIM * N_DIM, N_DIM,
            qh, 8, 144);
  }
}